// Round 16
// baseline (3522.088 us; speedup 1.0000x reference)
//
#include <hip/hip_runtime.h>
#include <cstdint>
#include <cstddef>

#define NROWS   131072
#define IN_DIM    56
#define H_DIM    512
#define D_DIM    256
#define K_CODES 1024

#define L1_SCALE  (1.0f / 7340032.0f)          // 1/(N*56)
#define VQ_SCALE  (5.0f / 33554432.0f)         // 5/(N*256)
#define GAP_TH    0.05f                        // >> split-bf16 error (~3e-3)

#define CB_BOOK_STRIDE 262144                  // shorts per book (1024*256)
#define WBOOK          131072                  // shorts per weight book (512*256)

typedef __attribute__((ext_vector_type(8))) short short8v;   // 8 bf16 = 4 VGPR
typedef __attribute__((ext_vector_type(4))) float f32x4;

// async global->LDS DMA, 16B per lane.  LDS dest must be wave-uniform;
// global src is per-lane.
#define GLDS(g, l) __builtin_amdgcn_global_load_lds(                        \
    (const __attribute__((address_space(1))) unsigned int*)(g),             \
    (__attribute__((address_space(3))) unsigned int*)(l), 16, 0, 0)

// f32 -> bf16 (RNE) as raw short; exact back-conversion
__device__ __forceinline__ short f2bf(float x)
{
    unsigned u = __float_as_uint(x);
    unsigned r = (u + 0x7FFFu + ((u >> 16) & 1u)) >> 16;
    return (short)r;
}
__device__ __forceinline__ float bf2f(short s)
{
    return __uint_as_float(((unsigned)(unsigned short)s) << 16);
}

// ---------------------------------------------------------------------------
// f32 tiled GEMM: C = act(A @ B + bias). Serial ascending-k fmaf chains.
// ROUND-1 body — used for the ENCODER (z must stay bit-identical).
// At its structural LDS ceiling (VALUBusy ~65%).
// ---------------------------------------------------------------------------
template<int ACT, bool GATHER_A, bool FUSE_L1>
__global__ __launch_bounds__(256)
void gemm_k(const float* __restrict__ A, const float* __restrict__ B,
            const float* __restrict__ bias, float* __restrict__ C,
            int Nc, int K,
            const int* __restrict__ gidx, const float* __restrict__ cbs,
            const float* __restrict__ Xref, float* __restrict__ out0)
{
    __shared__ float As[8][128];
    __shared__ float Bs[8][128];

    const int tid  = threadIdx.x;
    const int bm   = blockIdx.x * 128;
    const int bn   = blockIdx.y * 128;
    const int tx   = tid & 15;
    const int ty   = tid >> 4;
    const int arow = tid >> 1;
    const int ak   = (tid & 1) * 4;
    const int brow = tid >> 5;
    const int bcol = (tid & 31) * 4;

    float acc[8][8];
    #pragma unroll
    for (int i = 0; i < 8; i++)
        #pragma unroll
        for (int j = 0; j < 8; j++) acc[i][j] = 0.f;

    for (int k0 = 0; k0 < K; k0 += 8) {
        float4 av;
        if (GATHER_A) {
            const int n  = bm + arow;
            const int i0 = gidx[2 * n + 0];
            const int i1 = gidx[2 * n + 1];
            const float4 a0 = *(const float4*)(cbs + (size_t)i0 * D_DIM + k0 + ak);
            const float4 a1 = *(const float4*)(cbs + (size_t)K_CODES * D_DIM
                                               + (size_t)i1 * D_DIM + k0 + ak);
            av.x = a0.x + a1.x; av.y = a0.y + a1.y;
            av.z = a0.z + a1.z; av.w = a0.w + a1.w;
        } else {
            av = *(const float4*)(A + (size_t)(bm + arow) * K + k0 + ak);
        }
        As[ak + 0][arow] = av.x;
        As[ak + 1][arow] = av.y;
        As[ak + 2][arow] = av.z;
        As[ak + 3][arow] = av.w;

        float4 bv; bv.x = bv.y = bv.z = bv.w = 0.f;
        if (bn + bcol + 4 <= Nc)
            bv = *(const float4*)(B + (size_t)(k0 + brow) * Nc + bn + bcol);
        *(float4*)&Bs[brow][bcol] = bv;

        __syncthreads();

        #pragma unroll
        for (int kk = 0; kk < 8; kk++) {
            float a[8], b[8];
            float4 t;
            t = *(const float4*)&As[kk][ty * 4];      a[0]=t.x; a[1]=t.y; a[2]=t.z; a[3]=t.w;
            t = *(const float4*)&As[kk][64 + ty * 4]; a[4]=t.x; a[5]=t.y; a[6]=t.z; a[7]=t.w;
            t = *(const float4*)&Bs[kk][tx * 4];      b[0]=t.x; b[1]=t.y; b[2]=t.z; b[3]=t.w;
            t = *(const float4*)&Bs[kk][64 + tx * 4]; b[4]=t.x; b[5]=t.y; b[6]=t.z; b[7]=t.w;
            #pragma unroll
            for (int i = 0; i < 8; i++)
                #pragma unroll
                for (int j = 0; j < 8; j++)
                    acc[i][j] = fmaf(a[i], b[j], acc[i][j]);
        }
        __syncthreads();
    }

    if (!FUSE_L1) {
        #pragma unroll
        for (int i = 0; i < 8; i++) {
            const int row = bm + ((i < 4) ? ty * 4 + i : 64 + ty * 4 + i - 4);
            #pragma unroll
            for (int jg = 0; jg < 2; jg++) {
                const int c = bn + jg * 64 + tx * 4;
                if (c + 4 <= Nc) {
                    float v0 = acc[i][jg * 4 + 0] + bias[c + 0];
                    float v1 = acc[i][jg * 4 + 1] + bias[c + 1];
                    float v2 = acc[i][jg * 4 + 2] + bias[c + 2];
                    float v3 = acc[i][jg * 4 + 3] + bias[c + 3];
                    if (ACT == 1) {
                        v0 = fmaxf(v0, 0.f); v1 = fmaxf(v1, 0.f);
                        v2 = fmaxf(v2, 0.f); v3 = fmaxf(v3, 0.f);
                    }
                    float4 o; o.x = v0; o.y = v1; o.z = v2; o.w = v3;
                    *(float4*)(C + (size_t)row * Nc + c) = o;
                }
            }
        }
    } else {
        float lsum = 0.f;
        #pragma unroll
        for (int i = 0; i < 8; i++) {
            const int row = bm + ((i < 4) ? ty * 4 + i : 64 + ty * 4 + i - 4);
            #pragma unroll
            for (int j = 0; j < 8; j++) {
                const int c = bn + ((j < 4) ? tx * 4 + j : 64 + tx * 4 + j - 4);
                if (c < Nc) {
                    const float v = acc[i][j] + bias[c];
                    lsum += fabsf(Xref[(size_t)row * Nc + c] - v);
                }
            }
        }
        #pragma unroll
        for (int off = 32; off > 0; off >>= 1)
            lsum += __shfl_down(lsum, off, 64);
        __shared__ float sred[4];
        if ((tid & 63) == 0) sred[tid >> 6] = lsum;
        __syncthreads();
        if (tid == 0)
            atomicAdd(out0, (sred[0] + sred[1] + sred[2] + sred[3]) * L1_SCALE);
    }
}

// cnorm64[c] = sum_d cb[c][d]^2 in f64
__global__ __launch_bounds__(256)
void cnorm64_k(const float* __restrict__ cb, double* __restrict__ cnorm)
{
    const int c   = blockIdx.x;
    const int tid = threadIdx.x;
    const double v = (double)cb[(size_t)c * D_DIM + tid];
    double s = v * v;
    #pragma unroll
    for (int off = 32; off > 0; off >>= 1)
        s += __shfl_down(s, off, 64);
    __shared__ double sr[4];
    if ((tid & 63) == 0) sr[tid >> 6] = s;
    __syncthreads();
    if (tid == 0) cnorm[c] = sr[0] + sr[1] + sr[2] + sr[3];
}

// ---------------------------------------------------------------------------
// Split both codebooks into bf16 hi/lo arrays in the TILE-SWIZZLED layout
// (16-code x 256-k tiles = 8KB, linearly DMA-able, conflict-free ds_read).
// ---------------------------------------------------------------------------
__global__ __launch_bounds__(256)
void cbcvt_k(const float* __restrict__ cbs, short* __restrict__ cbh,
             short* __restrict__ cbl)
{
    const int cg  = blockIdx.x;          // 0..2047 (book*1024 + code)
    const int k   = threadIdx.x;         // 0..255
    const int book = cg >> 10;
    const int c    = cg & 1023;
    const float v = cbs[(size_t)cg * 256 + k];
    const short h = f2bf(v);
    const size_t idx = (size_t)book * CB_BOOK_STRIDE
                     + (size_t)(c >> 4) * 4096 + (size_t)(k >> 5) * 512
                     + (size_t)((k >> 3) & 3) * 128 + (size_t)(c & 15) * 8
                     + (size_t)(k & 7);
    cbh[idx] = h;
    cbl[idx] = f2bf(v - bf2f(h));
}

// ---------------------------------------------------------------------------
// Split a 256-row slab of a weight matrix W[K,ncols] (rows koff..koff+255)
// into TRANSPOSED tile-swizzled bf16 hi/lo books ([col][k] tiles).
// ---------------------------------------------------------------------------
__global__ __launch_bounds__(256)
void wcvt_k(const float* __restrict__ W, int ncols, int koff,
            short* __restrict__ bh, short* __restrict__ bl)
{
    const int c = blockIdx.x;            // output column
    const int k = threadIdx.x;           // 0..255 within slab
    const float v = W[(size_t)(koff + k) * ncols + c];
    const short h = f2bf(v);
    const size_t idx = (size_t)(c >> 4) * 4096 + (size_t)(k >> 5) * 512
                     + (size_t)((k >> 3) & 3) * 128 + (size_t)(c & 15) * 8
                     + (size_t)(k & 7);
    bh[idx] = h;
    bl[idx] = f2bf(v - bf2f(h));
}

// ---------------------------------------------------------------------------
// dec_w3 [512][56] -> padded 64-col book, 8 tiles ordered (kslab*4 + coltile)
// each 16 cols x 256 k.  Cols 56..63 are zero (pad -> zero acc contribution).
// ---------------------------------------------------------------------------
__global__ __launch_bounds__(256)
void wcvt3_k(const float* __restrict__ W, short* __restrict__ bh,
             short* __restrict__ bl)
{
    const int c  = blockIdx.x;           // 0..63
    const int ks = blockIdx.y;           // 0..1
    const int k  = threadIdx.x;          // 0..255
    float v = 0.f;
    if (c < 56) v = W[(size_t)(ks * 256 + k) * 56 + c];
    const short h = f2bf(v);
    const size_t idx = (size_t)(ks * 4 + (c >> 4)) * 4096
                     + (size_t)(k >> 5) * 512 + (size_t)((k >> 3) & 3) * 128
                     + (size_t)(c & 15) * 8 + (size_t)(k & 7);
    bh[idx] = h;
    bl[idx] = f2bf(v - bf2f(h));
}

// ---------------------------------------------------------------------------
// MFMA VQ sweep (round 16): counted-vmcnt double-buffer (m201/T3-T4 pattern).
// Per tile: issue stage(t+1) [4 GLDS], s_waitcnt vmcnt(4) (drains stage(t),
// keeps stage(t+1) IN FLIGHT across the barrier), raw s_barrier, compute,
// second s_barrier (read/write separation: iter t+1's DMA overwrites the
// buffer read here).  cn64 is hoisted to an LDS f32 table in the prologue
// so the in-loop vmcnt count sees ONLY the 4 GLDS (value bit-identical to
// the old per-tile (float)cn64[code]).  Distances/comparator unchanged.
// ---------------------------------------------------------------------------
__global__ __launch_bounds__(256)
void vqmf_k(const float* __restrict__ RIN, const short* __restrict__ cbhs,
            const short* __restrict__ cbls, const double* __restrict__ cn64,
            float4* __restrict__ part)
{
    __shared__ short Bsm[2][8192];       // [buf][h:0..4095 | l:4096..8191]
    __shared__ float cnf_s[1024];

    const int tid  = threadIdx.x;
    const int bm   = blockIdx.x * 64;
    const int w    = tid >> 6;           // wave 0..3 -> rows w*16..w*16+15
    const int l    = tid & 63;
    const int lrow = l & 15;             // A-row / B-code within tile
    const int lk   = (l >> 4) * 8;       // lane k-offset within K=32

    short8v zh[8], zl[8];
    const float* zp = RIN + (size_t)(bm + w * 16 + lrow) * 256 + lk;
    #pragma unroll
    for (int kt = 0; kt < 8; kt++) {
        const float4 a0 = *(const float4*)(zp + kt * 32);
        const float4 a1 = *(const float4*)(zp + kt * 32 + 4);
        float xv[8];
        xv[0]=a0.x; xv[1]=a0.y; xv[2]=a0.z; xv[3]=a0.w;
        xv[4]=a1.x; xv[5]=a1.y; xv[6]=a1.z; xv[7]=a1.w;
        #pragma unroll
        for (int e = 0; e < 8; e++) {
            const float x = 2.0f * xv[e];
            const short h = f2bf(x);
            zh[kt][e] = h;
            zl[kt][e] = f2bf(x - bf2f(h));
        }
    }

    // cn64 -> f32 LDS table (same value as the old (float)cn64[code])
    for (int i = tid; i < 1024; i += 256) cnf_s[i] = (float)cn64[i];

    float v1[4], v2[4];
    int   i1[4], i2[4];
    #pragma unroll
    for (int r = 0; r < 4; r++) { v1[r] = 3.4e38f; v2[r] = 3.4e38f; i1[r] = 0; i2[r] = 0; }

    const int soff = w * 512 + l * 8;

    // prologue: stage tile 0 into buf 0
    #pragma unroll
    for (int r = 0; r < 2; r++) {
        GLDS(cbhs + r * 2048 + soff, &Bsm[0][r * 2048 + w * 512]);
        GLDS(cbls + r * 2048 + soff, &Bsm[0][4096 + r * 2048 + w * 512]);
    }

    for (int t = 0; t < 64; t++) {
        const int buf = t & 1;
        if (t < 63) {
            const short* th = cbhs + (size_t)(t + 1) * 4096;
            const short* tl = cbls + (size_t)(t + 1) * 4096;
            #pragma unroll
            for (int r = 0; r < 2; r++) {
                GLDS(th + r * 2048 + soff, &Bsm[buf ^ 1][r * 2048 + w * 512]);
                GLDS(tl + r * 2048 + soff, &Bsm[buf ^ 1][4096 + r * 2048 + w * 512]);
            }
            // drain stage(t); keep stage(t+1)'s 4 GLDS in flight
            asm volatile("s_waitcnt vmcnt(4)" ::: "memory");
        } else {
            asm volatile("s_waitcnt vmcnt(0)" ::: "memory");
        }
        __builtin_amdgcn_s_barrier();    // all waves' stage(t) complete

        f32x4 acc = {0.f, 0.f, 0.f, 0.f};
        #pragma unroll
        for (int kt = 0; kt < 8; kt++) {
            const int fo = kt * 512 + (l >> 4) * 128 + lrow * 8;
            const short8v bh = *(const short8v*)&Bsm[buf][fo];
            const short8v bl = *(const short8v*)&Bsm[buf][4096 + fo];
            acc = __builtin_amdgcn_mfma_f32_16x16x32_bf16(zl[kt], bh, acc, 0, 0, 0);
            acc = __builtin_amdgcn_mfma_f32_16x16x32_bf16(zh[kt], bl, acc, 0, 0, 0);
            acc = __builtin_amdgcn_mfma_f32_16x16x32_bf16(zh[kt], bh, acc, 0, 0, 0);
        }

        const int code = t * 16 + lrow;
        const float cnf = cnf_s[code];
        #pragma unroll
        for (int r = 0; r < 4; r++) {
            const float v = cnf - acc[r];
            if (v < v1[r] || (v == v1[r] && code < i1[r])) {
                v2[r] = v1[r]; i2[r] = i1[r]; v1[r] = v; i1[r] = code;
            } else if (v < v2[r] || (v == v2[r] && code < i2[r])) {
                v2[r] = v; i2[r] = code;
            }
        }
        __builtin_amdgcn_s_barrier();    // readers done before t+1's DMA lands
    }

    #pragma unroll
    for (int m = 1; m <= 8; m <<= 1) {
        #pragma unroll
        for (int r = 0; r < 4; r++) {
            const float pV1 = __shfl_xor(v1[r], m, 64);
            const int   pI1 = __shfl_xor(i1[r], m, 64);
            const float pV2 = __shfl_xor(v2[r], m, 64);
            const int   pI2 = __shfl_xor(i2[r], m, 64);
            if (pV1 < v1[r] || (pV1 == v1[r] && pI1 < i1[r])) {
                v2[r] = v1[r]; i2[r] = i1[r]; v1[r] = pV1; i1[r] = pI1;
            } else if (pV1 < v2[r] || (pV1 == v2[r] && pI1 < i2[r])) {
                v2[r] = pV1; i2[r] = pI1;
            }
            if (pV2 < v1[r] || (pV2 == v1[r] && pI2 < i1[r])) {
                v2[r] = v1[r]; i2[r] = i1[r]; v1[r] = pV2; i1[r] = pI2;
            } else if (pV2 < v2[r] || (pV2 == v2[r] && pI2 < i2[r])) {
                v2[r] = pV2; i2[r] = pI2;
            }
        }
    }

    if (lrow == 0) {
        #pragma unroll
        for (int r = 0; r < 4; r++) {
            float4 o;
            o.x = v1[r]; o.y = __int_as_float(i1[r]);
            o.z = v2[r]; o.w = __int_as_float(i2[r]);
            part[(size_t)(bm + w * 16 + (l >> 4) * 4 + r)] = o;
        }
    }
}

// ---------------------------------------------------------------------------
// DECODER MFMA GEMM: Cout[:,0:512] = act(A @ Wbook + bias [+Cin]).
// Split-bf16 3-MFMA chain; feeds only the L1 loss (error ~1e-6 in the mean).
// (unchanged — its epilogue has in-loop global ops, so counted vmcnt is
//  fragile here; left on the __syncthreads drain.)
// ---------------------------------------------------------------------------
template<bool GATHER, bool ADDC, bool RELU, bool BIAS>
__global__ __launch_bounds__(256)
void dmf_k(const float* __restrict__ Ain, int lda, int aoff,
           const int* __restrict__ gidx, const float* __restrict__ cbs,
           const short* __restrict__ bhs, const short* __restrict__ bls,
           const float* __restrict__ bias,
           const float* __restrict__ Cin, float* __restrict__ Cout)
{
    __shared__ short Bsm[2][8192];

    const int tid  = threadIdx.x;
    const int bm   = blockIdx.x * 64;
    const int w    = tid >> 6;
    const int l    = tid & 63;
    const int lrow = l & 15;
    const int lk   = (l >> 4) * 8;

    short8v zh[8], zl[8];
    {
        const float* p0;
        const float* p1 = nullptr;
        if constexpr (GATHER) {
            const int n = bm + w * 16 + lrow;
            p0 = cbs + (size_t)gidx[2 * n + 0] * D_DIM + lk;
            p1 = cbs + (size_t)K_CODES * D_DIM
               + (size_t)gidx[2 * n + 1] * D_DIM + lk;
        } else {
            p0 = Ain + (size_t)(bm + w * 16 + lrow) * lda + aoff + lk;
        }
        #pragma unroll
        for (int kt = 0; kt < 8; kt++) {
            float xv[8];
            const float4 a0 = *(const float4*)(p0 + kt * 32);
            const float4 a1 = *(const float4*)(p0 + kt * 32 + 4);
            xv[0]=a0.x; xv[1]=a0.y; xv[2]=a0.z; xv[3]=a0.w;
            xv[4]=a1.x; xv[5]=a1.y; xv[6]=a1.z; xv[7]=a1.w;
            if constexpr (GATHER) {
                const float4 b0 = *(const float4*)(p1 + kt * 32);
                const float4 b1 = *(const float4*)(p1 + kt * 32 + 4);
                xv[0]+=b0.x; xv[1]+=b0.y; xv[2]+=b0.z; xv[3]+=b0.w;
                xv[4]+=b1.x; xv[5]+=b1.y; xv[6]+=b1.z; xv[7]+=b1.w;
            }
            #pragma unroll
            for (int e = 0; e < 8; e++) {
                const short h = f2bf(xv[e]);
                zh[kt][e] = h;
                zl[kt][e] = f2bf(xv[e] - bf2f(h));
            }
        }
    }

    const int soff = w * 512 + l * 8;
    #pragma unroll
    for (int r = 0; r < 2; r++) {
        GLDS(bhs + r * 2048 + soff, &Bsm[0][r * 2048 + w * 512]);
        GLDS(bls + r * 2048 + soff, &Bsm[0][4096 + r * 2048 + w * 512]);
    }
    __syncthreads();

    for (int t = 0; t < 32; t++) {
        const int buf = t & 1;
        if (t < 31) {
            const short* th = bhs + (size_t)(t + 1) * 4096;
            const short* tl = bls + (size_t)(t + 1) * 4096;
            #pragma unroll
            for (int r = 0; r < 2; r++) {
                GLDS(th + r * 2048 + soff, &Bsm[buf ^ 1][r * 2048 + w * 512]);
                GLDS(tl + r * 2048 + soff, &Bsm[buf ^ 1][4096 + r * 2048 + w * 512]);
            }
        }

        f32x4 acc = {0.f, 0.f, 0.f, 0.f};
        #pragma unroll
        for (int kt = 0; kt < 8; kt++) {
            const int fo = kt * 512 + (l >> 4) * 128 + lrow * 8;
            const short8v bh = *(const short8v*)&Bsm[buf][fo];
            const short8v bl = *(const short8v*)&Bsm[buf][4096 + fo];
            acc = __builtin_amdgcn_mfma_f32_16x16x32_bf16(zl[kt], bh, acc, 0, 0, 0);
            acc = __builtin_amdgcn_mfma_f32_16x16x32_bf16(zh[kt], bl, acc, 0, 0, 0);
            acc = __builtin_amdgcn_mfma_f32_16x16x32_bf16(zh[kt], bh, acc, 0, 0, 0);
        }

        const int col = t * 16 + lrow;
        float bv = 0.f;
        if constexpr (BIAS) bv = bias[col];
        #pragma unroll
        for (int r = 0; r < 4; r++) {
            const int row = bm + w * 16 + (l >> 4) * 4 + r;
            float v = acc[r];
            if constexpr (ADDC) v += Cin[(size_t)row * 512 + col];
            if constexpr (BIAS) v += bv;
            if constexpr (RELU) v = fmaxf(v, 0.f);
            Cout[(size_t)row * 512 + col] = v;
        }
        __syncthreads();
    }
}

// ---------------------------------------------------------------------------
// dec3 MFMA + fused L1 (round 15, unchanged): v = h2 @ dec_w3 + b3 (64
// padded cols, K=512 as 2 k-slabs x 4 col-tiles), lsum += |x - v| col<56.
// ---------------------------------------------------------------------------
__global__ __launch_bounds__(256)
void dmf3_k(const float* __restrict__ h2, const float* __restrict__ Xref,
            const short* __restrict__ bhs, const short* __restrict__ bls,
            const float* __restrict__ b3, float* __restrict__ out0)
{
    __shared__ short Bsm[2][8192];

    const int tid  = threadIdx.x;
    const int bm   = blockIdx.x * 64;
    const int w    = tid >> 6;
    const int l    = tid & 63;
    const int lrow = l & 15;
    const int lk   = (l >> 4) * 8;
    const int soff = w * 512 + l * 8;

    f32x4 acc[4];
    #pragma unroll
    for (int ct = 0; ct < 4; ct++) {
        acc[ct][0] = 0.f; acc[ct][1] = 0.f; acc[ct][2] = 0.f; acc[ct][3] = 0.f;
    }

    #pragma unroll
    for (int r = 0; r < 2; r++) {
        GLDS(bhs + r * 2048 + soff, &Bsm[0][r * 2048 + w * 512]);
        GLDS(bls + r * 2048 + soff, &Bsm[0][4096 + r * 2048 + w * 512]);
    }
    __syncthreads();

    #pragma unroll
    for (int ks = 0; ks < 2; ks++) {
        short8v zh[8], zl[8];
        const float* p0 = h2 + (size_t)(bm + w * 16 + lrow) * 512 + ks * 256 + lk;
        #pragma unroll
        for (int kt = 0; kt < 8; kt++) {
            float xv[8];
            const float4 a0 = *(const float4*)(p0 + kt * 32);
            const float4 a1 = *(const float4*)(p0 + kt * 32 + 4);
            xv[0]=a0.x; xv[1]=a0.y; xv[2]=a0.z; xv[3]=a0.w;
            xv[4]=a1.x; xv[5]=a1.y; xv[6]=a1.z; xv[7]=a1.w;
            #pragma unroll
            for (int e = 0; e < 8; e++) {
                const short h = f2bf(xv[e]);
                zh[kt][e] = h;
                zl[kt][e] = f2bf(xv[e] - bf2f(h));
            }
        }
        #pragma unroll
        for (int ct = 0; ct < 4; ct++) {
            const int t   = ks * 4 + ct;
            const int buf = t & 1;
            if (t < 7) {
                const short* th = bhs + (size_t)(t + 1) * 4096;
                const short* tl = bls + (size_t)(t + 1) * 4096;
                #pragma unroll
                for (int r = 0; r < 2; r++) {
                    GLDS(th + r * 2048 + soff, &Bsm[buf ^ 1][r * 2048 + w * 512]);
                    GLDS(tl + r * 2048 + soff, &Bsm[buf ^ 1][4096 + r * 2048 + w * 512]);
                }
            }
            f32x4 a = acc[ct];
            #pragma unroll
            for (int kt = 0; kt < 8; kt++) {
                const int fo = kt * 512 + (l >> 4) * 128 + lrow * 8;
                const short8v bh = *(const short8v*)&Bsm[buf][fo];
                const short8v bl = *(const short8v*)&Bsm[buf][4096 + fo];
                a = __builtin_amdgcn_mfma_f32_16x16x32_bf16(zl[kt], bh, a, 0, 0, 0);
                a = __builtin_amdgcn_mfma_f32_16x16x32_bf16(zh[kt], bl, a, 0, 0, 0);
                a = __builtin_amdgcn_mfma_f32_16x16x32_bf16(zh[kt], bh, a, 0, 0, 0);
            }
            acc[ct] = a;
            __syncthreads();
        }
    }

    float lsum = 0.f;
    #pragma unroll
    for (int ct = 0; ct < 4; ct++) {
        const int col = ct * 16 + lrow;
        if (col < 56) {
            const float bv = b3[col];
            #pragma unroll
            for (int r = 0; r < 4; r++) {
                const int row = bm + w * 16 + (l >> 4) * 4 + r;
                const float v = acc[ct][r] + bv;
                lsum += fabsf(Xref[(size_t)row * 56 + col] - v);
            }
        }
    }
    #pragma unroll
    for (int off = 32; off > 0; off >>= 1)
        lsum += __shfl_down(lsum, off, 64);
    __shared__ float sred[4];
    if ((tid & 63) == 0) sred[tid >> 6] = lsum;
    __syncthreads();
    if (tid == 0)
        atomicAdd(out0, (sred[0] + sred[1] + sred[2] + sred[3]) * L1_SCALE);
}

// ---------------------------------------------------------------------------
// Fused: read the final top-2 per row from part, write codes/idxw/gapA/altA/
// clist; then residual + commitment loss.  (round-9 version, unchanged)
// ---------------------------------------------------------------------------
__global__ __launch_bounds__(256)
void resid_k(const float* __restrict__ RIN, float* __restrict__ ROUT,
             const float* __restrict__ cb, const float4* __restrict__ part,
             int* __restrict__ idxw, float* __restrict__ codes_out,
             float* __restrict__ gapA, int* __restrict__ altA,
             int* __restrict__ cnt, int* __restrict__ clist,
             int qslot, int srow, int mrows, float* __restrict__ out0)
{
    __shared__ int widxs[128];
    const int tid = threadIdx.x;
    const int bm  = blockIdx.x * 128;

    if (tid < 128) {
        const int l = bm + tid;
        const float4 p0 = part[l];
        const float V1 = p0.x;  const int I1 = __float_as_int(p0.y);
        const float V2 = p0.z;  const int I2 = __float_as_int(p0.w);
        const int g = srow + l;
        codes_out[(size_t)g * 2 + qslot] = (float)I1;
        idxw[(size_t)l * 2 + qslot] = I1;
        widxs[tid] = I1;
        int dd = I2 - I1; if (dd < 0) dd = -dd;
        gapA[(size_t)qslot * NROWS + g] = (dd > 20) ? (V2 - V1) : 3.4e38f;
        altA[(size_t)qslot * NROWS + g] = I2;
        if (V2 - V1 < GAP_TH) {
            const int p = atomicAdd(cnt, 1);
            if (p < mrows) clist[p] = g;
        }
    }
    __syncthreads();

    double lsum = 0.0;
    for (int e = tid * 4; e < 128 * 256; e += 1024) {
        const int row  = e >> 8;
        const int d    = e & 255;
        const int widx = widxs[row];
        const float4 rv4 = *(const float4*)(RIN + (size_t)(bm + row) * 256 + d);
        const float4 cv4 = *(const float4*)(cb  + (size_t)widx * 256 + d);
        const float dx = rv4.x - cv4.x;
        const float dy = rv4.y - cv4.y;
        const float dz = rv4.z - cv4.z;
        const float dw = rv4.w - cv4.w;
        lsum += (double)dx * dx + (double)dy * dy
              + (double)dz * dz + (double)dw * dw;
        if (ROUT) {
            float4 o; o.x = dx; o.y = dy; o.z = dz; o.w = dw;
            *(float4*)(ROUT + (size_t)(bm + row) * 256 + d) = o;
        }
    }
    #pragma unroll
    for (int off = 32; off > 0; off >>= 1)
        lsum += __shfl_down(lsum, off, 64);
    __shared__ double sred[4];
    if ((tid & 63) == 0) sred[tid >> 6] = lsum;
    __syncthreads();
    if (tid == 0)
        atomicAdd(out0, (float)((sred[0] + sred[1] + sred[2] + sred[3]) * (double)VQ_SCALE));
}

// ---------------------------------------------------------------------------
// Exact f64 recheck of candidate rows (unchanged).
// ---------------------------------------------------------------------------
__global__ __launch_bounds__(256)
void recheck_k(const float* __restrict__ RIN, float* __restrict__ ROUT,
               const float* __restrict__ cb, float* __restrict__ codes_out,
               int* __restrict__ idxw, float* __restrict__ gapA,
               int* __restrict__ altA, const int* __restrict__ cnt,
               const int* __restrict__ clist, int qslot, int srow, int mrows)
{
    __shared__ float  zrow[256];
    __shared__ double tv1[256], tv2[256];
    __shared__ int    ti1[256], ti2[256];
    __shared__ int    sNew, sOld;

    const int tid = threadIdx.x;
    int total = cnt[0];
    if (total > mrows) total = mrows;

    for (int ci = blockIdx.x; ci < total; ci += gridDim.x) {
        const int g = clist[ci];
        const int l = g - srow;
        zrow[tid] = RIN[(size_t)l * 256 + tid];
        __syncthreads();

        double bv1 = 1e300, bv2 = 1e300;
        int    bi1 = 0,     bi2 = 0;
        #pragma unroll
        for (int j = 0; j < 4; j++) {
            const int c = tid * 4 + j;
            const float* cp = cb + (size_t)c * 256;
            double s = 0.0;
            for (int d = 0; d < 256; d++) {
                const double df = (double)zrow[d] - (double)cp[d];
                s = fma(df, df, s);
            }
            if (s < bv1 || (s == bv1 && c < bi1)) {
                bv2 = bv1; bi2 = bi1; bv1 = s; bi1 = c;
            } else if (s < bv2 || (s == bv2 && c < bi2)) {
                bv2 = s; bi2 = c;
            }
        }
        tv1[tid] = bv1; ti1[tid] = bi1;
        tv2[tid] = bv2; ti2[tid] = bi2;
        __syncthreads();

        for (int off = 128; off > 0; off >>= 1) {
            if (tid < off) {
                const double a1 = tv1[tid],       a2 = tv2[tid];
                const int    x1 = ti1[tid],       x2 = ti2[tid];
                const double b1 = tv1[tid + off], b2 = tv2[tid + off];
                const int    y1 = ti1[tid + off], y2 = ti2[tid + off];
                if (b1 < a1 || (b1 == a1 && y1 < x1)) {
                    tv1[tid] = b1; ti1[tid] = y1;
                    if (a1 < b2 || (a1 == b2 && x1 < y2)) { tv2[tid] = a1; ti2[tid] = x1; }
                    else                                   { tv2[tid] = b2; ti2[tid] = y2; }
                } else {
                    if (b1 < a2 || (b1 == a2 && y1 < x2)) { tv2[tid] = b1; ti2[tid] = y1; }
                }
            }
            __syncthreads();
        }

        if (tid == 0) {
            const int    I1 = ti1[0], I2 = ti2[0];
            const double V1 = tv1[0], V2 = tv2[0];
            const int oldI = idxw[(size_t)l * 2 + qslot];
            int dd = I2 - I1; if (dd < 0) dd = -dd;
            gapA[(size_t)qslot * NROWS + g] = (dd > 20) ? (float)(V2 - V1) : 3.4e38f;
            altA[(size_t)qslot * NROWS + g] = I2;
            sNew = I1; sOld = oldI;
            if (I1 != oldI) {
                codes_out[(size_t)g * 2 + qslot] = (float)I1;
                idxw[(size_t)l * 2 + qslot] = I1;
            }
        }
        __syncthreads();

        if (ROUT && sNew != sOld)
            ROUT[(size_t)l * 256 + tid] = zrow[tid] - cb[(size_t)sNew * 256 + tid];
        __syncthreads();
    }
}

// stage-1 reduce: 256 blocks x 1024 entries -> per-block (gap, entry)
__global__ __launch_bounds__(256)
void reduce1_k(const float* __restrict__ gapA, float* __restrict__ pgap,
               int* __restrict__ pidx)
{
    const int b   = blockIdx.x;
    const int tid = threadIdx.x;
    float bv = 3.4e38f; int be = 0;
    #pragma unroll
    for (int t = 0; t < 4; t++) {
        const int e = b * 1024 + t * 256 + tid;
        const float v = gapA[e];
        if (v < bv) { bv = v; be = e; }
    }
    __shared__ float sv[256];
    __shared__ int   se[256];
    sv[tid] = bv; se[tid] = be;
    __syncthreads();
    for (int off = 128; off > 0; off >>= 1) {
        if (tid < off && sv[tid + off] < sv[tid]) {
            sv[tid] = sv[tid + off]; se[tid] = se[tid + off];
        }
        __syncthreads();
    }
    if (tid == 0) { pgap[b] = sv[0]; pidx[b] = se[0]; }
}

// stage-2 reduce: 256 partials -> decision {row, q, alt, valid}
__global__ __launch_bounds__(256)
void reduce2_k(const float* __restrict__ pgap, const int* __restrict__ pidx,
               const int* __restrict__ altA, int* __restrict__ dec)
{
    const int tid = threadIdx.x;
    __shared__ float sv[256];
    __shared__ int   se[256];
    sv[tid] = pgap[tid]; se[tid] = pidx[tid];
    __syncthreads();
    for (int off = 128; off > 0; off >>= 1) {
        if (tid < off && sv[tid + off] < sv[tid]) {
            sv[tid] = sv[tid + off]; se[tid] = se[tid + off];
        }
        __syncthreads();
    }
    if (tid == 0) {
        const int e = se[0];
        const int q = e / NROWS;
        dec[0] = e - q * NROWS;
        dec[1] = q;
        dec[2] = altA[e];
        dec[3] = (sv[0] < 3.3e38f) ? 1 : 0;
    }
}

// flip the chosen entry; if stage 0, recompute that row's stage-1 code
__global__ __launch_bounds__(256)
void fixup_k(const int* __restrict__ dec, float* __restrict__ codes_out,
             const float* __restrict__ x,
             const float* __restrict__ w1, const float* __restrict__ b1,
             const float* __restrict__ w2, const float* __restrict__ b2,
             const float* __restrict__ w3, const float* __restrict__ b3,
             const float* __restrict__ cbs)
{
    const int tid = threadIdx.x;
    const int row = dec[0], q = dec[1], alt = dec[2], valid = dec[3];
    if (!valid) return;
    if (tid == 0) codes_out[(size_t)row * 2 + q] = (float)alt;
    if (q == 1) return;

    __shared__ float xs[56], h1[512], h2[512], r0[256];
    __shared__ double sdv[256];
    __shared__ int    sdi[256];

    if (tid < 56) xs[tid] = x[(size_t)row * IN_DIM + tid];
    __syncthreads();

    for (int c = tid; c < H_DIM; c += 256) {
        float a = 0.f;
        for (int k = 0; k < IN_DIM; k++) a = fmaf(xs[k], w1[(size_t)k * H_DIM + c], a);
        a += b1[c];
        h1[c] = fmaxf(a, 0.f);
    }
    __syncthreads();
    for (int c = tid; c < H_DIM; c += 256) {
        float a = 0.f;
        for (int k = 0; k < H_DIM; k++) a = fmaf(h1[k], w2[(size_t)k * H_DIM + c], a);
        a += b2[c];
        h2[c] = fmaxf(a, 0.f);
    }
    __syncthreads();
    if (tid < D_DIM) {
        float a = 0.f;
        for (int k = 0; k < H_DIM; k++) a = fmaf(h2[k], w3[(size_t)k * D_DIM + tid], a);
        a += b3[tid];
        r0[tid] = a - cbs[(size_t)alt * D_DIM + tid];
    }
    __syncthreads();

    double bv = 1e300; int bi = 0;
    for (int j = 0; j < 4; j++) {
        const int c = tid * 4 + j;
        const float* cp = cbs + (size_t)(K_CODES + c) * D_DIM;
        double s = 0.0;
        for (int d = 0; d < D_DIM; d++) {
            const double df = (double)r0[d] - (double)cp[d];
            s = fma(df, df, s);
        }
        if (s < bv) { bv = s; bi = c; }
    }
    sdv[tid] = bv; sdi[tid] = bi;
    __syncthreads();
    for (int off = 128; off > 0; off >>= 1) {
        if (tid < off) {
            if (sdv[tid + off] < sdv[tid] ||
                (sdv[tid + off] == sdv[tid] && sdi[tid + off] < sdi[tid])) {
                sdv[tid] = sdv[tid + off]; sdi[tid] = sdi[tid + off];
            }
        }
        __syncthreads();
    }
    if (tid == 0) codes_out[(size_t)row * 2 + 1] = (float)sdi[0];
}

__global__ void init_k(float* __restrict__ out, int* __restrict__ counters, int n)
{
    const int tid = threadIdx.x;
    for (int i = tid; i < n; i += 256) counters[i] = 0;
    if (tid == 0) out[0] = 0.0f;
}

extern "C" void kernel_launch(void* const* d_in, const int* in_sizes, int n_in,
                              void* d_out, int out_size, void* d_ws, size_t ws_size,
                              hipStream_t stream)
{
    const float* x      = (const float*)d_in[0];
    const float* enc_w1 = (const float*)d_in[1];
    const float* enc_b1 = (const float*)d_in[2];
    const float* enc_w2 = (const float*)d_in[3];
    const float* enc_b2 = (const float*)d_in[4];
    const float* enc_w3 = (const float*)d_in[5];
    const float* enc_b3 = (const float*)d_in[6];
    const float* dec_w1 = (const float*)d_in[7];
    const float* dec_b1 = (const float*)d_in[8];
    const float* dec_w2 = (const float*)d_in[9];
    const float* dec_b2 = (const float*)d_in[10];
    const float* dec_w3 = (const float*)d_in[11];
    const float* dec_b3 = (const float*)d_in[12];
    const float* cbs    = (const float*)d_in[13];

    // head: gapA/altA/clist 3MB + part 512KB + cbh/cbl 2MB + weight books
    char* ws = (char*)d_ws;
    size_t off = 0;
    float*  gapA  = (float*)(ws + off);  off += (size_t)2 * NROWS * 4;
    int*    altA  = (int*)(ws + off);    off += (size_t)2 * NROWS * 4;
    int*    clist = (int*)(ws + off);    off += (size_t)2 * NROWS * 4;
    float4* part  = (float4*)(ws + off); off += (size_t)32768 * 16;
    short*  cbh   = (short*)(ws + off);  off += (size_t)2 * CB_BOOK_STRIDE * 2;
    short*  cbl   = (short*)(ws + off);  off += (size_t)2 * CB_BOOK_STRIDE * 2;
    short*  wt1h  = (short*)(ws + off);  off += (size_t)WBOOK * 2;
    short*  wt1l  = (short*)(ws + off);  off += (size_t)WBOOK * 2;
    short*  w2ah  = (short*)(ws + off);  off += (size_t)WBOOK * 2;
    short*  w2al  = (short*)(ws + off);  off += (size_t)WBOOK * 2;
    short*  w2bh  = (short*)(ws + off);  off += (size_t)WBOOK * 2;
    short*  w2bl  = (short*)(ws + off);  off += (size_t)WBOOK * 2;
    short*  w3h   = (short*)(ws + off);  off += (size_t)32768 * 2;
    short*  w3l   = (short*)(ws + off);  off += (size_t)32768 * 2;
    double* cn64  = (double*)(ws + off); off += (size_t)2 * K_CODES * 8;
    int*    ctrs  = (int*)(ws + off);    off += 2048 * 4;
    float*  pgap  = (float*)(ws + off);  off += 256 * 4;
    int*    pidx  = (int*)(ws + off);    off += 256 * 4;
    int*    dec   = (int*)(ws + off);    off += 64;
    off = (off + 255) & ~(size_t)255;

    // chunk scratch: h1(2048)+h2(2048)+z(1024)+R1(1024)+idx(8) = 6152 B/row
    // M = 32768: per-chunk working set (~200MB) stays L3-resident — M=65536
    // (round 13) thrashed the 256MB L3 and regressed 15%.
    const size_t per_row = (size_t)(H_DIM + H_DIM + D_DIM + D_DIM) * 4 + 8;
    size_t usable = (ws_size > off) ? ws_size - off : 0;
    int M = (int)((usable / per_row) / 128) * 128;
    if (M > 32768) M = 32768;
    if (M < 128)   M = 128;

    float* h1   = (float*)(ws + off);
    float* h2   = h1 + (size_t)M * H_DIM;
    float* z    = h2 + (size_t)M * H_DIM;
    float* R1   = z  + (size_t)M * D_DIM;
    int*   idxw = (int*)(R1 + (size_t)M * D_DIM);

    float* out0      = (float*)d_out;
    float* codes_out = (float*)d_out + 1;

    init_k<<<1, 256, 0, stream>>>(out0, ctrs, 2048);
    cnorm64_k<<<2 * K_CODES, 256, 0, stream>>>(cbs, cn64);
    cbcvt_k<<<2 * K_CODES, 256, 0, stream>>>(cbs, cbh, cbl);
    wcvt_k<<<512, 256, 0, stream>>>(dec_w1, H_DIM, 0,   wt1h, wt1l);
    wcvt_k<<<512, 256, 0, stream>>>(dec_w2, H_DIM, 0,   w2ah, w2al);
    wcvt_k<<<512, 256, 0, stream>>>(dec_w2, H_DIM, 256, w2bh, w2bl);
    wcvt3_k<<<dim3(64, 2), 256, 0, stream>>>(dec_w3, w3h, w3l);

    const dim3 blk(256);
    int ci = 0;
    for (int s = 0; s < NROWS; s += M, ci++) {
        const int m    = (NROWS - s < M) ? (NROWS - s) : M;
        const int g128 = m / 128;
        const int g64  = m / 64;
        const float* xs  = x + (size_t)s * IN_DIM;
        const float* cb1 = cbs + (size_t)K_CODES * D_DIM;
        const short* cbh1 = cbh + (size_t)CB_BOOK_STRIDE;
        const short* cbl1 = cbl + (size_t)CB_BOOK_STRIDE;

        // encoder — bit-identical chains (z must not move)
        gemm_k<1, false, false><<<dim3(g128, 4), blk, 0, stream>>>(
            xs, enc_w1, enc_b1, h1, H_DIM, IN_DIM, nullptr, nullptr, nullptr, nullptr);
        gemm_k<1, false, false><<<dim3(g128, 4), blk, 0, stream>>>(
            h1, enc_w2, enc_b2, h2, H_DIM, H_DIM, nullptr, nullptr, nullptr, nullptr);
        gemm_k<0, false, false><<<dim3(g128, 2), blk, 0, stream>>>(
            h2, enc_w3, enc_b3, z, D_DIM, H_DIM, nullptr, nullptr, nullptr, nullptr);

        // residual VQ: DMA-staged MFMA sweep + fused top2/residual + recheck
        vqmf_k<<<g64, blk, 0, stream>>>(z, cbh, cbl, cn64, part);
        resid_k<<<g128, blk, 0, stream>>>(
            z, R1, cbs, part, idxw, codes_out, gapA, altA,
            ctrs + ci * 2 + 0, clist + 0 * NROWS + s, 0, s, m, out0);
        recheck_k<<<128, blk, 0, stream>>>(
            z, R1, cbs, codes_out, idxw, gapA, altA,
            ctrs + ci * 2 + 0, clist + 0 * NROWS + s, 0, s, m);
        vqmf_k<<<g64, blk, 0, stream>>>(R1, cbh1, cbl1, cn64 + K_CODES, part);
        resid_k<<<g128, blk, 0, stream>>>(
            R1, nullptr, cb1, part, idxw, codes_out, gapA, altA,
            ctrs + ci * 2 + 1, clist + 1 * NROWS + s, 1, s, m, out0);
        recheck_k<<<128, blk, 0, stream>>>(
            R1, nullptr, cb1, codes_out, idxw, gapA, altA,
            ctrs + ci * 2 + 1, clist + 1 * NROWS + s, 1, s, m);

        // decoder — MFMA (split-bf16) for dec1/dec2/dec3 (dec3 fuses L1)
        dmf_k<true, false, true, true><<<g64, blk, 0, stream>>>(
            nullptr, 0, 0, idxw, cbs, wt1h, wt1l, dec_b1, nullptr, h1);
        dmf_k<false, false, false, false><<<g64, blk, 0, stream>>>(
            h1, H_DIM, 0, nullptr, nullptr, w2ah, w2al, nullptr, nullptr, h2);
        dmf_k<false, true, true, true><<<g64, blk, 0, stream>>>(
            h1, H_DIM, 256, nullptr, nullptr, w2bh, w2bl, dec_b2, h2, h2);
        dmf3_k<<<g64, blk, 0, stream>>>(h2, xs, w3h, w3l, dec_b3, out0);
    }

    reduce1_k<<<256, blk, 0, stream>>>(gapA, pgap, pidx);
    reduce2_k<<<1, blk, 0, stream>>>(pgap, pidx, altA, dec);
    fixup_k<<<1, blk, 0, stream>>>(dec, codes_out, x,
                                   enc_w1, enc_b1, enc_w2, enc_b2, enc_w3, enc_b3,
                                   cbs);
}

// Round 17
// 3359.629 us; speedup vs baseline: 1.0484x; 1.0484x over previous
//
#include <hip/hip_runtime.h>
#include <cstdint>
#include <cstddef>

#define NROWS   131072
#define IN_DIM    56
#define H_DIM    512
#define D_DIM    256
#define K_CODES 1024

#define L1_SCALE  (1.0f / 7340032.0f)          // 1/(N*56)
#define VQ_SCALE  (5.0f / 33554432.0f)         // 5/(N*256)
#define GAP_TH    0.05f                        // >> split-bf16 error (~3e-3)

#define CB_BOOK_STRIDE 262144                  // shorts per book (1024*256)
#define WBOOK          131072                  // shorts per weight book (512*256)

typedef __attribute__((ext_vector_type(8))) short short8v;   // 8 bf16 = 4 VGPR
typedef __attribute__((ext_vector_type(4))) float f32x4;

// async global->LDS DMA, 16B per lane.  LDS dest must be wave-uniform;
// global src is per-lane.
#define GLDS(g, l) __builtin_amdgcn_global_load_lds(                        \
    (const __attribute__((address_space(1))) unsigned int*)(g),             \
    (__attribute__((address_space(3))) unsigned int*)(l), 16, 0, 0)

// f32 -> bf16 (RNE) as raw short; exact back-conversion
__device__ __forceinline__ short f2bf(float x)
{
    unsigned u = __float_as_uint(x);
    unsigned r = (u + 0x7FFFu + ((u >> 16) & 1u)) >> 16;
    return (short)r;
}
__device__ __forceinline__ float bf2f(short s)
{
    return __uint_as_float(((unsigned)(unsigned short)s) << 16);
}

// ---------------------------------------------------------------------------
// f32 tiled GEMM: C = act(A @ B + bias). Serial ascending-k fmaf chains.
// ROUND-1 body — used for the ENCODER (z must stay bit-identical).
// At its structural LDS ceiling (VALUBusy ~65%).
// ---------------------------------------------------------------------------
template<int ACT, bool GATHER_A, bool FUSE_L1>
__global__ __launch_bounds__(256)
void gemm_k(const float* __restrict__ A, const float* __restrict__ B,
            const float* __restrict__ bias, float* __restrict__ C,
            int Nc, int K,
            const int* __restrict__ gidx, const float* __restrict__ cbs,
            const float* __restrict__ Xref, float* __restrict__ out0)
{
    __shared__ float As[8][128];
    __shared__ float Bs[8][128];

    const int tid  = threadIdx.x;
    const int bm   = blockIdx.x * 128;
    const int bn   = blockIdx.y * 128;
    const int tx   = tid & 15;
    const int ty   = tid >> 4;
    const int arow = tid >> 1;
    const int ak   = (tid & 1) * 4;
    const int brow = tid >> 5;
    const int bcol = (tid & 31) * 4;

    float acc[8][8];
    #pragma unroll
    for (int i = 0; i < 8; i++)
        #pragma unroll
        for (int j = 0; j < 8; j++) acc[i][j] = 0.f;

    for (int k0 = 0; k0 < K; k0 += 8) {
        float4 av;
        if (GATHER_A) {
            const int n  = bm + arow;
            const int i0 = gidx[2 * n + 0];
            const int i1 = gidx[2 * n + 1];
            const float4 a0 = *(const float4*)(cbs + (size_t)i0 * D_DIM + k0 + ak);
            const float4 a1 = *(const float4*)(cbs + (size_t)K_CODES * D_DIM
                                               + (size_t)i1 * D_DIM + k0 + ak);
            av.x = a0.x + a1.x; av.y = a0.y + a1.y;
            av.z = a0.z + a1.z; av.w = a0.w + a1.w;
        } else {
            av = *(const float4*)(A + (size_t)(bm + arow) * K + k0 + ak);
        }
        As[ak + 0][arow] = av.x;
        As[ak + 1][arow] = av.y;
        As[ak + 2][arow] = av.z;
        As[ak + 3][arow] = av.w;

        float4 bv; bv.x = bv.y = bv.z = bv.w = 0.f;
        if (bn + bcol + 4 <= Nc)
            bv = *(const float4*)(B + (size_t)(k0 + brow) * Nc + bn + bcol);
        *(float4*)&Bs[brow][bcol] = bv;

        __syncthreads();

        #pragma unroll
        for (int kk = 0; kk < 8; kk++) {
            float a[8], b[8];
            float4 t;
            t = *(const float4*)&As[kk][ty * 4];      a[0]=t.x; a[1]=t.y; a[2]=t.z; a[3]=t.w;
            t = *(const float4*)&As[kk][64 + ty * 4]; a[4]=t.x; a[5]=t.y; a[6]=t.z; a[7]=t.w;
            t = *(const float4*)&Bs[kk][tx * 4];      b[0]=t.x; b[1]=t.y; b[2]=t.z; b[3]=t.w;
            t = *(const float4*)&Bs[kk][64 + tx * 4]; b[4]=t.x; b[5]=t.y; b[6]=t.z; b[7]=t.w;
            #pragma unroll
            for (int i = 0; i < 8; i++)
                #pragma unroll
                for (int j = 0; j < 8; j++)
                    acc[i][j] = fmaf(a[i], b[j], acc[i][j]);
        }
        __syncthreads();
    }

    if (!FUSE_L1) {
        #pragma unroll
        for (int i = 0; i < 8; i++) {
            const int row = bm + ((i < 4) ? ty * 4 + i : 64 + ty * 4 + i - 4);
            #pragma unroll
            for (int jg = 0; jg < 2; jg++) {
                const int c = bn + jg * 64 + tx * 4;
                if (c + 4 <= Nc) {
                    float v0 = acc[i][jg * 4 + 0] + bias[c + 0];
                    float v1 = acc[i][jg * 4 + 1] + bias[c + 1];
                    float v2 = acc[i][jg * 4 + 2] + bias[c + 2];
                    float v3 = acc[i][jg * 4 + 3] + bias[c + 3];
                    if (ACT == 1) {
                        v0 = fmaxf(v0, 0.f); v1 = fmaxf(v1, 0.f);
                        v2 = fmaxf(v2, 0.f); v3 = fmaxf(v3, 0.f);
                    }
                    float4 o; o.x = v0; o.y = v1; o.z = v2; o.w = v3;
                    *(float4*)(C + (size_t)row * Nc + c) = o;
                }
            }
        }
    } else {
        float lsum = 0.f;
        #pragma unroll
        for (int i = 0; i < 8; i++) {
            const int row = bm + ((i < 4) ? ty * 4 + i : 64 + ty * 4 + i - 4);
            #pragma unroll
            for (int j = 0; j < 8; j++) {
                const int c = bn + ((j < 4) ? tx * 4 + j : 64 + tx * 4 + j - 4);
                if (c < Nc) {
                    const float v = acc[i][j] + bias[c];
                    lsum += fabsf(Xref[(size_t)row * Nc + c] - v);
                }
            }
        }
        #pragma unroll
        for (int off = 32; off > 0; off >>= 1)
            lsum += __shfl_down(lsum, off, 64);
        __shared__ float sred[4];
        if ((tid & 63) == 0) sred[tid >> 6] = lsum;
        __syncthreads();
        if (tid == 0)
            atomicAdd(out0, (sred[0] + sred[1] + sred[2] + sred[3]) * L1_SCALE);
    }
}

// cnorm64[c] = sum_d cb[c][d]^2 in f64
__global__ __launch_bounds__(256)
void cnorm64_k(const float* __restrict__ cb, double* __restrict__ cnorm)
{
    const int c   = blockIdx.x;
    const int tid = threadIdx.x;
    const double v = (double)cb[(size_t)c * D_DIM + tid];
    double s = v * v;
    #pragma unroll
    for (int off = 32; off > 0; off >>= 1)
        s += __shfl_down(s, off, 64);
    __shared__ double sr[4];
    if ((tid & 63) == 0) sr[tid >> 6] = s;
    __syncthreads();
    if (tid == 0) cnorm[c] = sr[0] + sr[1] + sr[2] + sr[3];
}

// ---------------------------------------------------------------------------
// Split both codebooks into bf16 hi/lo arrays in the TILE-SWIZZLED layout
// (16-code x 256-k tiles = 8KB, linearly DMA-able, conflict-free ds_read).
// ---------------------------------------------------------------------------
__global__ __launch_bounds__(256)
void cbcvt_k(const float* __restrict__ cbs, short* __restrict__ cbh,
             short* __restrict__ cbl)
{
    const int cg  = blockIdx.x;          // 0..2047 (book*1024 + code)
    const int k   = threadIdx.x;         // 0..255
    const int book = cg >> 10;
    const int c    = cg & 1023;
    const float v = cbs[(size_t)cg * 256 + k];
    const short h = f2bf(v);
    const size_t idx = (size_t)book * CB_BOOK_STRIDE
                     + (size_t)(c >> 4) * 4096 + (size_t)(k >> 5) * 512
                     + (size_t)((k >> 3) & 3) * 128 + (size_t)(c & 15) * 8
                     + (size_t)(k & 7);
    cbh[idx] = h;
    cbl[idx] = f2bf(v - bf2f(h));
}

// ---------------------------------------------------------------------------
// Split a 256-row slab of a weight matrix W[K,ncols] (rows koff..koff+255)
// into TRANSPOSED tile-swizzled bf16 hi/lo books ([col][k] tiles).
// ---------------------------------------------------------------------------
__global__ __launch_bounds__(256)
void wcvt_k(const float* __restrict__ W, int ncols, int koff,
            short* __restrict__ bh, short* __restrict__ bl)
{
    const int c = blockIdx.x;            // output column
    const int k = threadIdx.x;           // 0..255 within slab
    const float v = W[(size_t)(koff + k) * ncols + c];
    const short h = f2bf(v);
    const size_t idx = (size_t)(c >> 4) * 4096 + (size_t)(k >> 5) * 512
                     + (size_t)((k >> 3) & 3) * 128 + (size_t)(c & 15) * 8
                     + (size_t)(k & 7);
    bh[idx] = h;
    bl[idx] = f2bf(v - bf2f(h));
}

// ---------------------------------------------------------------------------
// dec_w3 [512][56] -> padded 64-col book, 8 tiles ordered (kslab*4 + coltile)
// each 16 cols x 256 k.  Cols 56..63 are zero (pad -> zero acc contribution).
// ---------------------------------------------------------------------------
__global__ __launch_bounds__(256)
void wcvt3_k(const float* __restrict__ W, short* __restrict__ bh,
             short* __restrict__ bl)
{
    const int c  = blockIdx.x;           // 0..63
    const int ks = blockIdx.y;           // 0..1
    const int k  = threadIdx.x;          // 0..255
    float v = 0.f;
    if (c < 56) v = W[(size_t)(ks * 256 + k) * 56 + c];
    const short h = f2bf(v);
    const size_t idx = (size_t)(ks * 4 + (c >> 4)) * 4096
                     + (size_t)(k >> 5) * 512 + (size_t)((k >> 3) & 3) * 128
                     + (size_t)(c & 15) * 8 + (size_t)(k & 7);
    bh[idx] = h;
    bl[idx] = f2bf(v - bf2f(h));
}

// ---------------------------------------------------------------------------
// MFMA VQ sweep (round-15 version restored — __syncthreads-drained double
// buffer; round-16 counted-vmcnt was a null/regression, consistent with the
// compiler's near-optimal scheduling of the drain).
// ---------------------------------------------------------------------------
__global__ __launch_bounds__(256)
void vqmf_k(const float* __restrict__ RIN, const short* __restrict__ cbhs,
            const short* __restrict__ cbls, const double* __restrict__ cn64,
            float4* __restrict__ part)
{
    __shared__ short Bsm[2][8192];       // [buf][h:0..4095 | l:4096..8191]

    const int tid  = threadIdx.x;
    const int bm   = blockIdx.x * 64;
    const int w    = tid >> 6;           // wave 0..3 -> rows w*16..w*16+15
    const int l    = tid & 63;
    const int lrow = l & 15;             // A-row / B-code within tile
    const int lk   = (l >> 4) * 8;       // lane k-offset within K=32

    short8v zh[8], zl[8];
    const float* zp = RIN + (size_t)(bm + w * 16 + lrow) * 256 + lk;
    #pragma unroll
    for (int kt = 0; kt < 8; kt++) {
        const float4 a0 = *(const float4*)(zp + kt * 32);
        const float4 a1 = *(const float4*)(zp + kt * 32 + 4);
        float xv[8];
        xv[0]=a0.x; xv[1]=a0.y; xv[2]=a0.z; xv[3]=a0.w;
        xv[4]=a1.x; xv[5]=a1.y; xv[6]=a1.z; xv[7]=a1.w;
        #pragma unroll
        for (int e = 0; e < 8; e++) {
            const float x = 2.0f * xv[e];
            const short h = f2bf(x);
            zh[kt][e] = h;
            zl[kt][e] = f2bf(x - bf2f(h));
        }
    }

    float v1[4], v2[4];
    int   i1[4], i2[4];
    #pragma unroll
    for (int r = 0; r < 4; r++) { v1[r] = 3.4e38f; v2[r] = 3.4e38f; i1[r] = 0; i2[r] = 0; }

    const int soff = w * 512 + l * 8;

    #pragma unroll
    for (int r = 0; r < 2; r++) {
        GLDS(cbhs + r * 2048 + soff, &Bsm[0][r * 2048 + w * 512]);
        GLDS(cbls + r * 2048 + soff, &Bsm[0][4096 + r * 2048 + w * 512]);
    }
    __syncthreads();

    for (int t = 0; t < 64; t++) {
        const int buf = t & 1;
        if (t < 63) {
            const short* th = cbhs + (size_t)(t + 1) * 4096;
            const short* tl = cbls + (size_t)(t + 1) * 4096;
            #pragma unroll
            for (int r = 0; r < 2; r++) {
                GLDS(th + r * 2048 + soff, &Bsm[buf ^ 1][r * 2048 + w * 512]);
                GLDS(tl + r * 2048 + soff, &Bsm[buf ^ 1][4096 + r * 2048 + w * 512]);
            }
        }

        f32x4 acc = {0.f, 0.f, 0.f, 0.f};
        #pragma unroll
        for (int kt = 0; kt < 8; kt++) {
            const int fo = kt * 512 + (l >> 4) * 128 + lrow * 8;
            const short8v bh = *(const short8v*)&Bsm[buf][fo];
            const short8v bl = *(const short8v*)&Bsm[buf][4096 + fo];
            acc = __builtin_amdgcn_mfma_f32_16x16x32_bf16(zl[kt], bh, acc, 0, 0, 0);
            acc = __builtin_amdgcn_mfma_f32_16x16x32_bf16(zh[kt], bl, acc, 0, 0, 0);
            acc = __builtin_amdgcn_mfma_f32_16x16x32_bf16(zh[kt], bh, acc, 0, 0, 0);
        }

        const int code = t * 16 + lrow;
        const float cnf = (float)cn64[code];
        #pragma unroll
        for (int r = 0; r < 4; r++) {
            const float v = cnf - acc[r];
            if (v < v1[r] || (v == v1[r] && code < i1[r])) {
                v2[r] = v1[r]; i2[r] = i1[r]; v1[r] = v; i1[r] = code;
            } else if (v < v2[r] || (v == v2[r] && code < i2[r])) {
                v2[r] = v; i2[r] = code;
            }
        }
        __syncthreads();
    }

    #pragma unroll
    for (int m = 1; m <= 8; m <<= 1) {
        #pragma unroll
        for (int r = 0; r < 4; r++) {
            const float pV1 = __shfl_xor(v1[r], m, 64);
            const int   pI1 = __shfl_xor(i1[r], m, 64);
            const float pV2 = __shfl_xor(v2[r], m, 64);
            const int   pI2 = __shfl_xor(i2[r], m, 64);
            if (pV1 < v1[r] || (pV1 == v1[r] && pI1 < i1[r])) {
                v2[r] = v1[r]; i2[r] = i1[r]; v1[r] = pV1; i1[r] = pI1;
            } else if (pV1 < v2[r] || (pV1 == v2[r] && pI1 < i2[r])) {
                v2[r] = pV1; i2[r] = pI1;
            }
            if (pV2 < v1[r] || (pV2 == v1[r] && pI2 < i1[r])) {
                v2[r] = v1[r]; i2[r] = i1[r]; v1[r] = pV2; i1[r] = pI2;
            } else if (pV2 < v2[r] || (pV2 == v2[r] && pI2 < i2[r])) {
                v2[r] = pV2; i2[r] = pI2;
            }
        }
    }

    if (lrow == 0) {
        #pragma unroll
        for (int r = 0; r < 4; r++) {
            float4 o;
            o.x = v1[r]; o.y = __int_as_float(i1[r]);
            o.z = v2[r]; o.w = __int_as_float(i2[r]);
            part[(size_t)(bm + w * 16 + (l >> 4) * 4 + r)] = o;
        }
    }
}

// ---------------------------------------------------------------------------
// DECODER MFMA GEMM: Cout[:,0:512] = act(A @ Wbook + bias [+Cin]).
// Split-bf16 3-MFMA chain; feeds only the L1 loss (error ~1e-6 in the mean).
// ---------------------------------------------------------------------------
template<bool GATHER, bool ADDC, bool RELU, bool BIAS>
__global__ __launch_bounds__(256)
void dmf_k(const float* __restrict__ Ain, int lda, int aoff,
           const int* __restrict__ gidx, const float* __restrict__ cbs,
           const short* __restrict__ bhs, const short* __restrict__ bls,
           const float* __restrict__ bias,
           const float* __restrict__ Cin, float* __restrict__ Cout)
{
    __shared__ short Bsm[2][8192];

    const int tid  = threadIdx.x;
    const int bm   = blockIdx.x * 64;
    const int w    = tid >> 6;
    const int l    = tid & 63;
    const int lrow = l & 15;
    const int lk   = (l >> 4) * 8;

    short8v zh[8], zl[8];
    {
        const float* p0;
        const float* p1 = nullptr;
        if constexpr (GATHER) {
            const int n = bm + w * 16 + lrow;
            p0 = cbs + (size_t)gidx[2 * n + 0] * D_DIM + lk;
            p1 = cbs + (size_t)K_CODES * D_DIM
               + (size_t)gidx[2 * n + 1] * D_DIM + lk;
        } else {
            p0 = Ain + (size_t)(bm + w * 16 + lrow) * lda + aoff + lk;
        }
        #pragma unroll
        for (int kt = 0; kt < 8; kt++) {
            float xv[8];
            const float4 a0 = *(const float4*)(p0 + kt * 32);
            const float4 a1 = *(const float4*)(p0 + kt * 32 + 4);
            xv[0]=a0.x; xv[1]=a0.y; xv[2]=a0.z; xv[3]=a0.w;
            xv[4]=a1.x; xv[5]=a1.y; xv[6]=a1.z; xv[7]=a1.w;
            if constexpr (GATHER) {
                const float4 b0 = *(const float4*)(p1 + kt * 32);
                const float4 b1 = *(const float4*)(p1 + kt * 32 + 4);
                xv[0]+=b0.x; xv[1]+=b0.y; xv[2]+=b0.z; xv[3]+=b0.w;
                xv[4]+=b1.x; xv[5]+=b1.y; xv[6]+=b1.z; xv[7]+=b1.w;
            }
            #pragma unroll
            for (int e = 0; e < 8; e++) {
                const short h = f2bf(xv[e]);
                zh[kt][e] = h;
                zl[kt][e] = f2bf(xv[e] - bf2f(h));
            }
        }
    }

    const int soff = w * 512 + l * 8;
    #pragma unroll
    for (int r = 0; r < 2; r++) {
        GLDS(bhs + r * 2048 + soff, &Bsm[0][r * 2048 + w * 512]);
        GLDS(bls + r * 2048 + soff, &Bsm[0][4096 + r * 2048 + w * 512]);
    }
    __syncthreads();

    for (int t = 0; t < 32; t++) {
        const int buf = t & 1;
        if (t < 31) {
            const short* th = bhs + (size_t)(t + 1) * 4096;
            const short* tl = bls + (size_t)(t + 1) * 4096;
            #pragma unroll
            for (int r = 0; r < 2; r++) {
                GLDS(th + r * 2048 + soff, &Bsm[buf ^ 1][r * 2048 + w * 512]);
                GLDS(tl + r * 2048 + soff, &Bsm[buf ^ 1][4096 + r * 2048 + w * 512]);
            }
        }

        f32x4 acc = {0.f, 0.f, 0.f, 0.f};
        #pragma unroll
        for (int kt = 0; kt < 8; kt++) {
            const int fo = kt * 512 + (l >> 4) * 128 + lrow * 8;
            const short8v bh = *(const short8v*)&Bsm[buf][fo];
            const short8v bl = *(const short8v*)&Bsm[buf][4096 + fo];
            acc = __builtin_amdgcn_mfma_f32_16x16x32_bf16(zl[kt], bh, acc, 0, 0, 0);
            acc = __builtin_amdgcn_mfma_f32_16x16x32_bf16(zh[kt], bl, acc, 0, 0, 0);
            acc = __builtin_amdgcn_mfma_f32_16x16x32_bf16(zh[kt], bh, acc, 0, 0, 0);
        }

        const int col = t * 16 + lrow;
        float bv = 0.f;
        if constexpr (BIAS) bv = bias[col];
        #pragma unroll
        for (int r = 0; r < 4; r++) {
            const int row = bm + w * 16 + (l >> 4) * 4 + r;
            float v = acc[r];
            if constexpr (ADDC) v += Cin[(size_t)row * 512 + col];
            if constexpr (BIAS) v += bv;
            if constexpr (RELU) v = fmaxf(v, 0.f);
            Cout[(size_t)row * 512 + col] = v;
        }
        __syncthreads();
    }
}

// ---------------------------------------------------------------------------
// dec3 MFMA + fused L1: v = h2 @ dec_w3 + b3 (64 padded cols, K=512 as 2
// k-slabs x 4 col-tiles), lsum += |x - v| for col<56.
// ---------------------------------------------------------------------------
__global__ __launch_bounds__(256)
void dmf3_k(const float* __restrict__ h2, const float* __restrict__ Xref,
            const short* __restrict__ bhs, const short* __restrict__ bls,
            const float* __restrict__ b3, float* __restrict__ out0)
{
    __shared__ short Bsm[2][8192];

    const int tid  = threadIdx.x;
    const int bm   = blockIdx.x * 64;
    const int w    = tid >> 6;
    const int l    = tid & 63;
    const int lrow = l & 15;
    const int lk   = (l >> 4) * 8;
    const int soff = w * 512 + l * 8;

    f32x4 acc[4];
    #pragma unroll
    for (int ct = 0; ct < 4; ct++) {
        acc[ct][0] = 0.f; acc[ct][1] = 0.f; acc[ct][2] = 0.f; acc[ct][3] = 0.f;
    }

    #pragma unroll
    for (int r = 0; r < 2; r++) {
        GLDS(bhs + r * 2048 + soff, &Bsm[0][r * 2048 + w * 512]);
        GLDS(bls + r * 2048 + soff, &Bsm[0][4096 + r * 2048 + w * 512]);
    }
    __syncthreads();

    #pragma unroll
    for (int ks = 0; ks < 2; ks++) {
        short8v zh[8], zl[8];
        const float* p0 = h2 + (size_t)(bm + w * 16 + lrow) * 512 + ks * 256 + lk;
        #pragma unroll
        for (int kt = 0; kt < 8; kt++) {
            float xv[8];
            const float4 a0 = *(const float4*)(p0 + kt * 32);
            const float4 a1 = *(const float4*)(p0 + kt * 32 + 4);
            xv[0]=a0.x; xv[1]=a0.y; xv[2]=a0.z; xv[3]=a0.w;
            xv[4]=a1.x; xv[5]=a1.y; xv[6]=a1.z; xv[7]=a1.w;
            #pragma unroll
            for (int e = 0; e < 8; e++) {
                const short h = f2bf(xv[e]);
                zh[kt][e] = h;
                zl[kt][e] = f2bf(xv[e] - bf2f(h));
            }
        }
        #pragma unroll
        for (int ct = 0; ct < 4; ct++) {
            const int t   = ks * 4 + ct;
            const int buf = t & 1;
            if (t < 7) {
                const short* th = bhs + (size_t)(t + 1) * 4096;
                const short* tl = bls + (size_t)(t + 1) * 4096;
                #pragma unroll
                for (int r = 0; r < 2; r++) {
                    GLDS(th + r * 2048 + soff, &Bsm[buf ^ 1][r * 2048 + w * 512]);
                    GLDS(tl + r * 2048 + soff, &Bsm[buf ^ 1][4096 + r * 2048 + w * 512]);
                }
            }
            f32x4 a = acc[ct];
            #pragma unroll
            for (int kt = 0; kt < 8; kt++) {
                const int fo = kt * 512 + (l >> 4) * 128 + lrow * 8;
                const short8v bh = *(const short8v*)&Bsm[buf][fo];
                const short8v bl = *(const short8v*)&Bsm[buf][4096 + fo];
                a = __builtin_amdgcn_mfma_f32_16x16x32_bf16(zl[kt], bh, a, 0, 0, 0);
                a = __builtin_amdgcn_mfma_f32_16x16x32_bf16(zh[kt], bl, a, 0, 0, 0);
                a = __builtin_amdgcn_mfma_f32_16x16x32_bf16(zh[kt], bh, a, 0, 0, 0);
            }
            acc[ct] = a;
            __syncthreads();
        }
    }

    float lsum = 0.f;
    #pragma unroll
    for (int ct = 0; ct < 4; ct++) {
        const int col = ct * 16 + lrow;
        if (col < 56) {
            const float bv = b3[col];
            #pragma unroll
            for (int r = 0; r < 4; r++) {
                const int row = bm + w * 16 + (l >> 4) * 4 + r;
                const float v = acc[ct][r] + bv;
                lsum += fabsf(Xref[(size_t)row * 56 + col] - v);
            }
        }
    }
    #pragma unroll
    for (int off = 32; off > 0; off >>= 1)
        lsum += __shfl_down(lsum, off, 64);
    __shared__ float sred[4];
    if ((tid & 63) == 0) sred[tid >> 6] = lsum;
    __syncthreads();
    if (tid == 0)
        atomicAdd(out0, (sred[0] + sred[1] + sred[2] + sred[3]) * L1_SCALE);
}

// ---------------------------------------------------------------------------
// Fused: read the final top-2 per row from part, write codes/idxw/gapA/altA/
// clist; then residual + commitment loss.
// ---------------------------------------------------------------------------
__global__ __launch_bounds__(256)
void resid_k(const float* __restrict__ RIN, float* __restrict__ ROUT,
             const float* __restrict__ cb, const float4* __restrict__ part,
             int* __restrict__ idxw, float* __restrict__ codes_out,
             float* __restrict__ gapA, int* __restrict__ altA,
             int* __restrict__ cnt, int* __restrict__ clist,
             int qslot, int srow, int mrows, float* __restrict__ out0)
{
    __shared__ int widxs[128];
    const int tid = threadIdx.x;
    const int bm  = blockIdx.x * 128;

    if (tid < 128) {
        const int l = bm + tid;
        const float4 p0 = part[l];
        const float V1 = p0.x;  const int I1 = __float_as_int(p0.y);
        const float V2 = p0.z;  const int I2 = __float_as_int(p0.w);
        const int g = srow + l;
        codes_out[(size_t)g * 2 + qslot] = (float)I1;
        idxw[(size_t)l * 2 + qslot] = I1;
        widxs[tid] = I1;
        int dd = I2 - I1; if (dd < 0) dd = -dd;
        gapA[(size_t)qslot * NROWS + g] = (dd > 20) ? (V2 - V1) : 3.4e38f;
        altA[(size_t)qslot * NROWS + g] = I2;
        if (V2 - V1 < GAP_TH) {
            const int p = atomicAdd(cnt, 1);
            if (p < mrows) clist[p] = g;
        }
    }
    __syncthreads();

    double lsum = 0.0;
    for (int e = tid * 4; e < 128 * 256; e += 1024) {
        const int row  = e >> 8;
        const int d    = e & 255;
        const int widx = widxs[row];
        const float4 rv4 = *(const float4*)(RIN + (size_t)(bm + row) * 256 + d);
        const float4 cv4 = *(const float4*)(cb  + (size_t)widx * 256 + d);
        const float dx = rv4.x - cv4.x;
        const float dy = rv4.y - cv4.y;
        const float dz = rv4.z - cv4.z;
        const float dw = rv4.w - cv4.w;
        lsum += (double)dx * dx + (double)dy * dy
              + (double)dz * dz + (double)dw * dw;
        if (ROUT) {
            float4 o; o.x = dx; o.y = dy; o.z = dz; o.w = dw;
            *(float4*)(ROUT + (size_t)(bm + row) * 256 + d) = o;
        }
    }
    #pragma unroll
    for (int off = 32; off > 0; off >>= 1)
        lsum += __shfl_down(lsum, off, 64);
    __shared__ double sred[4];
    if ((tid & 63) == 0) sred[tid >> 6] = lsum;
    __syncthreads();
    if (tid == 0)
        atomicAdd(out0, (float)((sred[0] + sred[1] + sred[2] + sred[3]) * (double)VQ_SCALE));
}

// ---------------------------------------------------------------------------
// Exact f64 recheck of candidate rows (unchanged).
// ---------------------------------------------------------------------------
__global__ __launch_bounds__(256)
void recheck_k(const float* __restrict__ RIN, float* __restrict__ ROUT,
               const float* __restrict__ cb, float* __restrict__ codes_out,
               int* __restrict__ idxw, float* __restrict__ gapA,
               int* __restrict__ altA, const int* __restrict__ cnt,
               const int* __restrict__ clist, int qslot, int srow, int mrows)
{
    __shared__ float  zrow[256];
    __shared__ double tv1[256], tv2[256];
    __shared__ int    ti1[256], ti2[256];
    __shared__ int    sNew, sOld;

    const int tid = threadIdx.x;
    int total = cnt[0];
    if (total > mrows) total = mrows;

    for (int ci = blockIdx.x; ci < total; ci += gridDim.x) {
        const int g = clist[ci];
        const int l = g - srow;
        zrow[tid] = RIN[(size_t)l * 256 + tid];
        __syncthreads();

        double bv1 = 1e300, bv2 = 1e300;
        int    bi1 = 0,     bi2 = 0;
        #pragma unroll
        for (int j = 0; j < 4; j++) {
            const int c = tid * 4 + j;
            const float* cp = cb + (size_t)c * 256;
            double s = 0.0;
            for (int d = 0; d < 256; d++) {
                const double df = (double)zrow[d] - (double)cp[d];
                s = fma(df, df, s);
            }
            if (s < bv1 || (s == bv1 && c < bi1)) {
                bv2 = bv1; bi2 = bi1; bv1 = s; bi1 = c;
            } else if (s < bv2 || (s == bv2 && c < bi2)) {
                bv2 = s; bi2 = c;
            }
        }
        tv1[tid] = bv1; ti1[tid] = bi1;
        tv2[tid] = bv2; ti2[tid] = bi2;
        __syncthreads();

        for (int off = 128; off > 0; off >>= 1) {
            if (tid < off) {
                const double a1 = tv1[tid],       a2 = tv2[tid];
                const int    x1 = ti1[tid],       x2 = ti2[tid];
                const double b1 = tv1[tid + off], b2 = tv2[tid + off];
                const int    y1 = ti1[tid + off], y2 = ti2[tid + off];
                if (b1 < a1 || (b1 == a1 && y1 < x1)) {
                    tv1[tid] = b1; ti1[tid] = y1;
                    if (a1 < b2 || (a1 == b2 && x1 < y2)) { tv2[tid] = a1; ti2[tid] = x1; }
                    else                                   { tv2[tid] = b2; ti2[tid] = y2; }
                } else {
                    if (b1 < a2 || (b1 == a2 && y1 < x2)) { tv2[tid] = b1; ti2[tid] = y1; }
                }
            }
            __syncthreads();
        }

        if (tid == 0) {
            const int    I1 = ti1[0], I2 = ti2[0];
            const double V1 = tv1[0], V2 = tv2[0];
            const int oldI = idxw[(size_t)l * 2 + qslot];
            int dd = I2 - I1; if (dd < 0) dd = -dd;
            gapA[(size_t)qslot * NROWS + g] = (dd > 20) ? (float)(V2 - V1) : 3.4e38f;
            altA[(size_t)qslot * NROWS + g] = I2;
            sNew = I1; sOld = oldI;
            if (I1 != oldI) {
                codes_out[(size_t)g * 2 + qslot] = (float)I1;
                idxw[(size_t)l * 2 + qslot] = I1;
            }
        }
        __syncthreads();

        if (ROUT && sNew != sOld)
            ROUT[(size_t)l * 256 + tid] = zrow[tid] - cb[(size_t)sNew * 256 + tid];
        __syncthreads();
    }
}

// stage-1 reduce: 256 blocks x 1024 entries -> per-block (gap, entry)
__global__ __launch_bounds__(256)
void reduce1_k(const float* __restrict__ gapA, float* __restrict__ pgap,
               int* __restrict__ pidx)
{
    const int b   = blockIdx.x;
    const int tid = threadIdx.x;
    float bv = 3.4e38f; int be = 0;
    #pragma unroll
    for (int t = 0; t < 4; t++) {
        const int e = b * 1024 + t * 256 + tid;
        const float v = gapA[e];
        if (v < bv) { bv = v; be = e; }
    }
    __shared__ float sv[256];
    __shared__ int   se[256];
    sv[tid] = bv; se[tid] = be;
    __syncthreads();
    for (int off = 128; off > 0; off >>= 1) {
        if (tid < off && sv[tid + off] < sv[tid]) {
            sv[tid] = sv[tid + off]; se[tid] = se[tid + off];
        }
        __syncthreads();
    }
    if (tid == 0) { pgap[b] = sv[0]; pidx[b] = se[0]; }
}

// stage-2 reduce: 256 partials -> decision {row, q, alt, valid}
__global__ __launch_bounds__(256)
void reduce2_k(const float* __restrict__ pgap, const int* __restrict__ pidx,
               const int* __restrict__ altA, int* __restrict__ dec)
{
    const int tid = threadIdx.x;
    __shared__ float sv[256];
    __shared__ int   se[256];
    sv[tid] = pgap[tid]; se[tid] = pidx[tid];
    __syncthreads();
    for (int off = 128; off > 0; off >>= 1) {
        if (tid < off && sv[tid + off] < sv[tid]) {
            sv[tid] = sv[tid + off]; se[tid] = se[tid + off];
        }
        __syncthreads();
    }
    if (tid == 0) {
        const int e = se[0];
        const int q = e / NROWS;
        dec[0] = e - q * NROWS;
        dec[1] = q;
        dec[2] = altA[e];
        dec[3] = (sv[0] < 3.3e38f) ? 1 : 0;
    }
}

// flip the chosen entry; if stage 0, recompute that row's stage-1 code
__global__ __launch_bounds__(256)
void fixup_k(const int* __restrict__ dec, float* __restrict__ codes_out,
             const float* __restrict__ x,
             const float* __restrict__ w1, const float* __restrict__ b1,
             const float* __restrict__ w2, const float* __restrict__ b2,
             const float* __restrict__ w3, const float* __restrict__ b3,
             const float* __restrict__ cbs)
{
    const int tid = threadIdx.x;
    const int row = dec[0], q = dec[1], alt = dec[2], valid = dec[3];
    if (!valid) return;
    if (tid == 0) codes_out[(size_t)row * 2 + q] = (float)alt;
    if (q == 1) return;

    __shared__ float xs[56], h1[512], h2[512], r0[256];
    __shared__ double sdv[256];
    __shared__ int    sdi[256];

    if (tid < 56) xs[tid] = x[(size_t)row * IN_DIM + tid];
    __syncthreads();

    for (int c = tid; c < H_DIM; c += 256) {
        float a = 0.f;
        for (int k = 0; k < IN_DIM; k++) a = fmaf(xs[k], w1[(size_t)k * H_DIM + c], a);
        a += b1[c];
        h1[c] = fmaxf(a, 0.f);
    }
    __syncthreads();
    for (int c = tid; c < H_DIM; c += 256) {
        float a = 0.f;
        for (int k = 0; k < H_DIM; k++) a = fmaf(h1[k], w2[(size_t)k * H_DIM + c], a);
        a += b2[c];
        h2[c] = fmaxf(a, 0.f);
    }
    __syncthreads();
    if (tid < D_DIM) {
        float a = 0.f;
        for (int k = 0; k < H_DIM; k++) a = fmaf(h2[k], w3[(size_t)k * D_DIM + tid], a);
        a += b3[tid];
        r0[tid] = a - cbs[(size_t)alt * D_DIM + tid];
    }
    __syncthreads();

    double bv = 1e300; int bi = 0;
    for (int j = 0; j < 4; j++) {
        const int c = tid * 4 + j;
        const float* cp = cbs + (size_t)(K_CODES + c) * D_DIM;
        double s = 0.0;
        for (int d = 0; d < D_DIM; d++) {
            const double df = (double)r0[d] - (double)cp[d];
            s = fma(df, df, s);
        }
        if (s < bv) { bv = s; bi = c; }
    }
    sdv[tid] = bv; sdi[tid] = bi;
    __syncthreads();
    for (int off = 128; off > 0; off >>= 1) {
        if (tid < off) {
            if (sdv[tid + off] < sdv[tid] ||
                (sdv[tid + off] == sdv[tid] && sdi[tid + off] < sdi[tid])) {
                sdv[tid] = sdv[tid + off]; sdi[tid] = sdi[tid + off];
            }
        }
        __syncthreads();
    }
    if (tid == 0) codes_out[(size_t)row * 2 + 1] = (float)sdi[0];
}

__global__ void init_k(float* __restrict__ out, int* __restrict__ counters, int n)
{
    const int tid = threadIdx.x;
    for (int i = tid; i < n; i += 256) counters[i] = 0;
    if (tid == 0) out[0] = 0.0f;
}

extern "C" void kernel_launch(void* const* d_in, const int* in_sizes, int n_in,
                              void* d_out, int out_size, void* d_ws, size_t ws_size,
                              hipStream_t stream)
{
    const float* x      = (const float*)d_in[0];
    const float* enc_w1 = (const float*)d_in[1];
    const float* enc_b1 = (const float*)d_in[2];
    const float* enc_w2 = (const float*)d_in[3];
    const float* enc_b2 = (const float*)d_in[4];
    const float* enc_w3 = (const float*)d_in[5];
    const float* enc_b3 = (const float*)d_in[6];
    const float* dec_w1 = (const float*)d_in[7];
    const float* dec_b1 = (const float*)d_in[8];
    const float* dec_w2 = (const float*)d_in[9];
    const float* dec_b2 = (const float*)d_in[10];
    const float* dec_w3 = (const float*)d_in[11];
    const float* dec_b3 = (const float*)d_in[12];
    const float* cbs    = (const float*)d_in[13];

    // head: gapA/altA/clist 3MB + part 512KB + cbh/cbl 2MB + weight books
    char* ws = (char*)d_ws;
    size_t off = 0;
    float*  gapA  = (float*)(ws + off);  off += (size_t)2 * NROWS * 4;
    int*    altA  = (int*)(ws + off);    off += (size_t)2 * NROWS * 4;
    int*    clist = (int*)(ws + off);    off += (size_t)2 * NROWS * 4;
    float4* part  = (float4*)(ws + off); off += (size_t)32768 * 16;
    short*  cbh   = (short*)(ws + off);  off += (size_t)2 * CB_BOOK_STRIDE * 2;
    short*  cbl   = (short*)(ws + off);  off += (size_t)2 * CB_BOOK_STRIDE * 2;
    short*  wt1h  = (short*)(ws + off);  off += (size_t)WBOOK * 2;
    short*  wt1l  = (short*)(ws + off);  off += (size_t)WBOOK * 2;
    short*  w2ah  = (short*)(ws + off);  off += (size_t)WBOOK * 2;
    short*  w2al  = (short*)(ws + off);  off += (size_t)WBOOK * 2;
    short*  w2bh  = (short*)(ws + off);  off += (size_t)WBOOK * 2;
    short*  w2bl  = (short*)(ws + off);  off += (size_t)WBOOK * 2;
    short*  w3h   = (short*)(ws + off);  off += (size_t)32768 * 2;
    short*  w3l   = (short*)(ws + off);  off += (size_t)32768 * 2;
    double* cn64  = (double*)(ws + off); off += (size_t)2 * K_CODES * 8;
    int*    ctrs  = (int*)(ws + off);    off += 2048 * 4;
    float*  pgap  = (float*)(ws + off);  off += 256 * 4;
    int*    pidx  = (int*)(ws + off);    off += 256 * 4;
    int*    dec   = (int*)(ws + off);    off += 64;
    off = (off + 255) & ~(size_t)255;

    // chunk scratch: h1(2048)+h2(2048)+z(1024)+R1(1024)+idx(8) = 6152 B/row
    // M = 32768: per-chunk working set (~200MB) stays L3-resident — M=65536
    // (round 13) thrashed the 256MB L3 and regressed 15%.
    const size_t per_row = (size_t)(H_DIM + H_DIM + D_DIM + D_DIM) * 4 + 8;
    size_t usable = (ws_size > off) ? ws_size - off : 0;
    int M = (int)((usable / per_row) / 128) * 128;
    if (M > 32768) M = 32768;
    if (M < 128)   M = 128;

    float* h1   = (float*)(ws + off);
    float* h2   = h1 + (size_t)M * H_DIM;
    float* z    = h2 + (size_t)M * H_DIM;
    float* R1   = z  + (size_t)M * D_DIM;
    int*   idxw = (int*)(R1 + (size_t)M * D_DIM);

    float* out0      = (float*)d_out;
    float* codes_out = (float*)d_out + 1;

    init_k<<<1, 256, 0, stream>>>(out0, ctrs, 2048);
    cnorm64_k<<<2 * K_CODES, 256, 0, stream>>>(cbs, cn64);
    cbcvt_k<<<2 * K_CODES, 256, 0, stream>>>(cbs, cbh, cbl);
    wcvt_k<<<512, 256, 0, stream>>>(dec_w1, H_DIM, 0,   wt1h, wt1l);
    wcvt_k<<<512, 256, 0, stream>>>(dec_w2, H_DIM, 0,   w2ah, w2al);
    wcvt_k<<<512, 256, 0, stream>>>(dec_w2, H_DIM, 256, w2bh, w2bl);
    wcvt3_k<<<dim3(64, 2), 256, 0, stream>>>(dec_w3, w3h, w3l);

    const dim3 blk(256);
    int ci = 0;
    for (int s = 0; s < NROWS; s += M, ci++) {
        const int m    = (NROWS - s < M) ? (NROWS - s) : M;
        const int g128 = m / 128;
        const int g64  = m / 64;
        const float* xs  = x + (size_t)s * IN_DIM;
        const float* cb1 = cbs + (size_t)K_CODES * D_DIM;
        const short* cbh1 = cbh + (size_t)CB_BOOK_STRIDE;
        const short* cbl1 = cbl + (size_t)CB_BOOK_STRIDE;

        // encoder — bit-identical chains (z must not move)
        gemm_k<1, false, false><<<dim3(g128, 4), blk, 0, stream>>>(
            xs, enc_w1, enc_b1, h1, H_DIM, IN_DIM, nullptr, nullptr, nullptr, nullptr);
        gemm_k<1, false, false><<<dim3(g128, 4), blk, 0, stream>>>(
            h1, enc_w2, enc_b2, h2, H_DIM, H_DIM, nullptr, nullptr, nullptr, nullptr);
        gemm_k<0, false, false><<<dim3(g128, 2), blk, 0, stream>>>(
            h2, enc_w3, enc_b3, z, D_DIM, H_DIM, nullptr, nullptr, nullptr, nullptr);

        // residual VQ: DMA-staged MFMA sweep + fused top2/residual + recheck
        vqmf_k<<<g64, blk, 0, stream>>>(z, cbh, cbl, cn64, part);
        resid_k<<<g128, blk, 0, stream>>>(
            z, R1, cbs, part, idxw, codes_out, gapA, altA,
            ctrs + ci * 2 + 0, clist + 0 * NROWS + s, 0, s, m, out0);
        recheck_k<<<128, blk, 0, stream>>>(
            z, R1, cbs, codes_out, idxw, gapA, altA,
            ctrs + ci * 2 + 0, clist + 0 * NROWS + s, 0, s, m);
        vqmf_k<<<g64, blk, 0, stream>>>(R1, cbh1, cbl1, cn64 + K_CODES, part);
        resid_k<<<g128, blk, 0, stream>>>(
            R1, nullptr, cb1, part, idxw, codes_out, gapA, altA,
            ctrs + ci * 2 + 1, clist + 1 * NROWS + s, 1, s, m, out0);
        recheck_k<<<128, blk, 0, stream>>>(
            R1, nullptr, cb1, codes_out, idxw, gapA, altA,
            ctrs + ci * 2 + 1, clist + 1 * NROWS + s, 1, s, m);

        // decoder — MFMA (split-bf16) for dec1/dec2/dec3 (dec3 fuses L1)
        dmf_k<true, false, true, true><<<g64, blk, 0, stream>>>(
            nullptr, 0, 0, idxw, cbs, wt1h, wt1l, dec_b1, nullptr, h1);
        dmf_k<false, false, false, false><<<g64, blk, 0, stream>>>(
            h1, H_DIM, 0, nullptr, nullptr, w2ah, w2al, nullptr, nullptr, h2);
        dmf_k<false, true, true, true><<<g64, blk, 0, stream>>>(
            h1, H_DIM, 256, nullptr, nullptr, w2bh, w2bl, dec_b2, h2, h2);
        dmf3_k<<<g64, blk, 0, stream>>>(h2, xs, w3h, w3l, dec_b3, out0);
    }

    reduce1_k<<<256, blk, 0, stream>>>(gapA, pgap, pidx);
    reduce2_k<<<1, blk, 0, stream>>>(pgap, pidx, altA, dec);
    fixup_k<<<1, blk, 0, stream>>>(dec, codes_out, x,
                                   enc_w1, enc_b1, enc_w2, enc_b2, enc_w3, enc_b3,
                                   cbs);
}